// Round 1
// baseline (994.290 us; speedup 1.0000x reference)
//
#include <hip/hip_runtime.h>
#include <hip/hip_bf16.h>
#include <cstdint>
#include <cstddef>

#define B_ 2
#define T_ 6
#define P_ 10000
#define DIMM 128
#define DSTAT 16
#define G0_ 3
#define G1_ 10
#define DCONV 3
#define NTOK (B_*T_*P_)   /* 120000 */
#define NWIN 4000         /* B * (T/G0) * (P/G1) */
#define LWIN 30

__device__ __forceinline__ float siluf_(float x){ return x/(1.f+expf(-x)); }
__device__ __forceinline__ float softplusf_(float x){ return fmaxf(x,0.f)+log1pf(expf(-fabsf(x))); }
__device__ __forceinline__ float geluf_(float x){ return 0.5f*x*(1.f+erff(x*0.70710678118654752f)); }

__device__ __forceinline__ void storev(float* p, float v){ *p = v; }
__device__ __forceinline__ void storev(__hip_bfloat16* p, float v){ *p = __float2bfloat16(v); }

// ---------------- prep: gather + LN + loan1 -> hpre [NTOK][128] ----------------
__global__ __launch_bounds__(128) void k_prep(
    const float* __restrict__ x, const float* __restrict__ xst,
    const int* __restrict__ curves,
    const float* __restrict__ loan1_w, const float* __restrict__ loan1_b,
    float* __restrict__ hpre)
{
  int token = blockIdx.x;
  int c = threadIdx.x;
  int b = token / (T_*P_);
  int t = (token / P_) % T_;
  int i = token % P_;
  int c0 = curves[(b*2 + 0)*P_ + i];
  size_t src = (size_t)(b*T_ + t)*P_ + c0;
  __shared__ float ssb[DSTAT];
  __shared__ float red[DIMM], red2[DIMM];
  float v = x[src*DIMM + c];
  if (c < DSTAT) ssb[c] = xst[src*DSTAT + c];
  red[c]=v; red2[c]=v*v;
  __syncthreads();
  for (int s=64; s>0; s>>=1){
    if (c < s){ red[c]+=red[c+s]; red2[c]+=red2[c+s]; }
    __syncthreads();
  }
  float m  = red[0]*(1.f/DIMM);
  float var = red2[0]*(1.f/DIMM) - m*m;
  float rs = rsqrtf(var + 1e-5f);
  float acc = loan1_b[c];
  #pragma unroll
  for (int j=0;j<DSTAT;j++) acc += ssb[j]*loan1_w[c*DSTAT+j];
  hpre[(size_t)token*DIMM + c] = (v - m)*rs + acc;
}

// ---------------- generic tiled f32 GEMM: C[M,N] = act(A[M,K] @ W[N,K]^T + bias) --------
template<typename OutT, int ACT>
__global__ __launch_bounds__(256) void k_gemm_nt(
    const float* __restrict__ A, const float* __restrict__ W,
    const float* __restrict__ bias, OutT* __restrict__ C,
    int M, int N, int K)
{
  __shared__ float As[64][17];
  __shared__ float Ws[64][17];
  int tid = threadIdx.x;
  int tx = tid & 15, ty = tid >> 4;
  int m0 = blockIdx.x * 64, n0 = blockIdx.y * 64;
  int r = tid >> 2, q = (tid & 3) * 4;
  float acc[4][4] = {{0.f}};
  for (int k0 = 0; k0 < K; k0 += 16) {
    float4 av = *reinterpret_cast<const float4*>(&A[(size_t)(m0 + r)*K + k0 + q]);
    float4 wv = *reinterpret_cast<const float4*>(&W[(size_t)(n0 + r)*K + k0 + q]);
    As[r][q+0]=av.x; As[r][q+1]=av.y; As[r][q+2]=av.z; As[r][q+3]=av.w;
    Ws[r][q+0]=wv.x; Ws[r][q+1]=wv.y; Ws[r][q+2]=wv.z; Ws[r][q+3]=wv.w;
    __syncthreads();
    #pragma unroll
    for (int kk=0; kk<16; ++kk) {
      float a_[4], b_[4];
      #pragma unroll
      for (int i2=0;i2<4;i2++) a_[i2] = As[ty*4+i2][kk];
      #pragma unroll
      for (int j=0;j<4;j++) b_[j] = Ws[tx*4+j][kk];
      #pragma unroll
      for (int i2=0;i2<4;i2++)
        #pragma unroll
        for (int j=0;j<4;j++) acc[i2][j] += a_[i2]*b_[j];
    }
    __syncthreads();
  }
  #pragma unroll
  for (int i2=0;i2<4;i2++){
    int m = m0 + ty*4 + i2;
    #pragma unroll
    for (int j=0;j<4;j++){
      int n = n0 + tx*4 + j;
      float v = acc[i2][j];
      if (bias) v += bias[n];
      if (ACT==1) v = geluf_(v);
      storev(&C[(size_t)m*N + n], v);
    }
  }
}

// ---------------- mamba per window (dir in {0,1}) ----------------
__global__ __launch_bounds__(128) void k_mamba(
    const __hip_bfloat16* __restrict__ H,      // [NTOK][256] bf16
    const float* __restrict__ conv_w, const float* __restrict__ conv_b,
    const float* __restrict__ xproj_w, const float* __restrict__ dt_w,
    const float* __restrict__ dt_b, const float* __restrict__ A_log,
    const float* __restrict__ Dp, float* __restrict__ Y)  // [2][NWIN][30][128]
{
  int dir = blockIdx.x / NWIN;
  int n   = blockIdx.x % NWIN;
  int c = threadIdx.x;
  int b  = n / 2000;
  int a  = (n / 1000) & 1;
  int qw = n % 1000;
  __shared__ float xh_s[LWIN][132];
  __shared__ float u_s[LWIN][132];
  __shared__ float z_s[LWIN][132];
  __shared__ float dt_s[LWIN][8];
  __shared__ float Bs[LWIN], Cs[LWIN];

  for (int l = 0; l < LWIN; ++l) {
    int t  = a*G0_ + l/G1_;
    int pf = qw*G1_ + l%G1_;
    int p  = dir ? (P_-1-pf) : pf;
    size_t base = ((size_t)((b*T_+t)*P_ + p))*256;
    xh_s[l][c] = __bfloat162float(H[base + c]);
    z_s[l][c]  = __bfloat162float(H[base + 128 + c]);
  }
  float w0 = conv_w[(dir*DIMM + c)*DCONV + 0];
  float w1 = conv_w[(dir*DIMM + c)*DCONV + 1];
  float w2 = conv_w[(dir*DIMM + c)*DCONV + 2];
  float cb = conv_b[dir*DIMM + c];
  __syncthreads();
  #pragma unroll
  for (int l=0;l<LWIN;l++){
    float xm2 = (l>=2)? xh_s[l-2][c] : 0.f;
    float xm1 = (l>=1)? xh_s[l-1][c] : 0.f;
    float xc = w0*xm2 + w1*xm1 + w2*xh_s[l][c] + cb;
    u_s[l][c] = siluf_(xc);
  }
  __syncthreads();
  const float* xpw = xproj_w + dir*10*DIMM;
  for (int task = c; task < 300; task += 128) {
    int l = task/10, j = task%10;
    float acc2 = 0.f;
    for (int k=0;k<DIMM;k++) acc2 += u_s[l][k]*xpw[j*DIMM+k];
    if (j < 8) dt_s[l][j] = acc2;
    else if (j==8) Bs[l] = acc2;
    else Cs[l] = acc2;
  }
  __syncthreads();
  float dtw[8];
  #pragma unroll
  for (int r2=0;r2<8;r2++) dtw[r2] = dt_w[dir*DIMM*8 + c*8 + r2];
  float dtbv = dt_b[dir*DIMM + c];
  float Av = -expf(A_log[dir*DIMM + c]);
  float Dv = Dp[dir*DIMM + c];
  float hst = 0.f;
  float* Yp = Y + ((size_t)dir*NWIN + n)*LWIN*DIMM;
  for (int l=0;l<LWIN;l++){
    float dtv = dtbv;
    #pragma unroll
    for (int r2=0;r2<8;r2++) dtv += dt_s[l][r2]*dtw[r2];
    float delta = softplusf_(dtv);
    float uv = u_s[l][c];
    hst = expf(delta*Av)*hst + delta*uv*Bs[l];
    float y = hst*Cs[l] + uv*Dv;
    float zv = z_s[l][c];
    y *= siluf_(zv);
    Yp[l*DIMM + c] = y;
  }
}

// ---------------- combine with the scrambled _wrev mapping ----------------
__device__ __forceinline__ int win_index(int t, int p){
  int G  = t*P_ + p;
  int d3 = G / 6000;
  int r  = G % 6000;
  int d1 = r / 6;
  int r2 = r % 6;
  int d4 = r2 >> 1;
  int d2 = r2 & 1;
  int F  = d1*60 + d2*30 + d3*3 + d4;
  int a  = F / 30000;
  int F2 = F % 30000;
  int qw = F2 / 30;
  int l  = F2 % 30;
  return (a*1000 + qw)*LWIN + l;   // per-batch window-element offset
}

__global__ __launch_bounds__(128) void k_combine(
    const float* __restrict__ Y, float* __restrict__ yc)
{
  int token = blockIdx.x; int c = threadIdx.x;
  int b = token/(T_*P_); int rem = token%(T_*P_);
  int t = rem/P_, p = rem%P_;
  size_t bbase = (size_t)b*2000*LWIN;
  int wf = win_index(t, p);
  int wb = win_index(t, P_-1-p);
  const float* Yf = Y;
  const float* Yb = Y + (size_t)NWIN*LWIN*DIMM;
  float vf = Yf[(bbase + wf)*DIMM + c];
  float vb = Yb[(bbase + wb)*DIMM + c];
  yc[(size_t)token*DIMM + c] = 0.5f*(vf+vb);
}

// ---------------- mid: x1 = xs + yproj ; g = LN(x1) + loan2 ----------------
__global__ __launch_bounds__(128) void k_mid(
    const float* __restrict__ x, const float* __restrict__ xst,
    const int* __restrict__ curves,
    const float* __restrict__ yproj,
    const float* __restrict__ loan2_w, const float* __restrict__ loan2_b,
    float* __restrict__ x1, float* __restrict__ g)
{
  int token = blockIdx.x;
  int c = threadIdx.x;
  int b = token / (T_*P_);
  int t = (token / P_) % T_;
  int i = token % P_;
  int c0 = curves[(b*2 + 0)*P_ + i];
  size_t src = (size_t)(b*T_ + t)*P_ + c0;
  __shared__ float ssb[DSTAT];
  __shared__ float red[DIMM], red2[DIMM];
  float v = x[src*DIMM + c] + yproj[(size_t)token*DIMM + c];
  x1[(size_t)token*DIMM + c] = v;
  if (c < DSTAT) ssb[c] = xst[src*DSTAT + c];
  red[c]=v; red2[c]=v*v;
  __syncthreads();
  for (int s=64; s>0; s>>=1){
    if (c < s){ red[c]+=red[c+s]; red2[c]+=red2[c+s]; }
    __syncthreads();
  }
  float m  = red[0]*(1.f/DIMM);
  float var = red2[0]*(1.f/DIMM) - m*m;
  float rs = rsqrtf(var + 1e-5f);
  float acc = loan2_b[c];
  #pragma unroll
  for (int j=0;j<DSTAT;j++) acc += ssb[j]*loan2_w[c*DSTAT+j];
  g[(size_t)token*DIMM + c] = (v - m)*rs + acc;
}

// ---------------- final: x2 = x1 + h2, gather by c1 ----------------
__global__ __launch_bounds__(128) void k_final(
    const float* __restrict__ x1, const float* __restrict__ h2,
    const int* __restrict__ curves, float* __restrict__ out)
{
  int token = blockIdx.x; int c = threadIdx.x;
  int b = token/(T_*P_); int rem = token%(T_*P_);
  int t = rem/P_, i = rem%P_;
  int c1 = curves[(b*2+1)*P_ + i];
  size_t src = (size_t)(b*T_+t)*P_ + c1;
  out[(size_t)token*DIMM + c] = x1[src*DIMM + c] + h2[src*DIMM + c];
}

extern "C" void kernel_launch(void* const* d_in, const int* in_sizes, int n_in,
                              void* d_out, int out_size, void* d_ws, size_t ws_size,
                              hipStream_t stream) {
  const float* x        = (const float*)d_in[0];
  const float* xst      = (const float*)d_in[1];
  const int*   curves   = (const int*)  d_in[2];
  const float* loan1_w  = (const float*)d_in[3];
  const float* loan1_b  = (const float*)d_in[4];
  const float* loan2_w  = (const float*)d_in[5];
  const float* loan2_b  = (const float*)d_in[6];
  const float* in_proj_w  = (const float*)d_in[7];
  const float* out_proj_w = (const float*)d_in[8];
  const float* conv_w   = (const float*)d_in[9];
  const float* conv_b   = (const float*)d_in[10];
  const float* xproj_w  = (const float*)d_in[11];
  const float* dt_w     = (const float*)d_in[12];
  const float* dt_b     = (const float*)d_in[13];
  const float* A_log    = (const float*)d_in[14];
  const float* Dvec     = (const float*)d_in[15];
  const float* fc1_w    = (const float*)d_in[16];
  const float* fc1_b    = (const float*)d_in[17];
  const float* fc2_w    = (const float*)d_in[18];
  const float* fc2_b    = (const float*)d_in[19];
  float* out = (float*)d_out;

  char* ws = (char*)d_ws;
  const size_t SEG = (size_t)NTOK*DIMM*sizeof(float); // 61,440,000 bytes
  float*          hpre  = (float*)(ws + 0*SEG);
  __hip_bfloat16* Hbf   = (__hip_bfloat16*)(ws + 1*SEG);  // NTOK*256*2B == SEG
  float*          Ybuf  = (float*)(ws + 2*SEG);           // 2 segs: Yf then Yb
  // aliases (lifetimes verified):
  float* ycomb = (float*)(ws + 0*SEG);   // over hpre (dead after gemm1)
  float* yproj = (float*)(ws + 1*SEG);   // over Hbf  (dead after mamba)
  float* x1    = (float*)(ws + 2*SEG);   // over Yf   (dead after combine)
  float* gmid  = (float*)(ws + 3*SEG);   // over Yb   (dead after combine)
  float* a1    = (float*)(ws + 0*SEG);   // over ycomb (dead after gemm2)
  float* h2    = (float*)(ws + 1*SEG);   // over yproj (dead after k_mid)

  k_prep<<<NTOK, 128, 0, stream>>>(x, xst, curves, loan1_w, loan1_b, hpre);

  dim3 g1(NTOK/64, 256/64);
  k_gemm_nt<__hip_bfloat16,0><<<g1, 256, 0, stream>>>(hpre, in_proj_w, nullptr, Hbf, NTOK, 256, 128);

  k_mamba<<<2*NWIN, 128, 0, stream>>>(Hbf, conv_w, conv_b, xproj_w, dt_w, dt_b, A_log, Dvec, Ybuf);

  k_combine<<<NTOK, 128, 0, stream>>>(Ybuf, ycomb);

  dim3 g2(NTOK/64, 128/64);
  k_gemm_nt<float,0><<<g2, 256, 0, stream>>>(ycomb, out_proj_w, nullptr, yproj, NTOK, 128, 128);

  k_mid<<<NTOK, 128, 0, stream>>>(x, xst, curves, yproj, loan2_w, loan2_b, x1, gmid);

  k_gemm_nt<float,1><<<g2, 256, 0, stream>>>(gmid, fc1_w, fc1_b, a1, NTOK, 128, 128);
  k_gemm_nt<float,0><<<g2, 256, 0, stream>>>(a1, fc2_w, fc2_b, h2, NTOK, 128, 128);

  k_final<<<NTOK, 128, 0, stream>>>(x1, h2, curves, out);
}

// Round 2
// 442.182 us; speedup vs baseline: 2.2486x; 2.2486x over previous
//
#include <hip/hip_runtime.h>
#include <hip/hip_bf16.h>
#include <cstdint>
#include <cstddef>

#define B_ 2
#define T_ 6
#define P_ 10000
#define DIMM 128
#define DSTAT 16
#define G0_ 3
#define G1_ 10
#define DCONV 3
#define NTOK (B_*T_*P_)   /* 120000 */
#define NWIN 4000         /* B * (T/G0) * (P/G1) */
#define LWIN 30

typedef __attribute__((ext_vector_type(8))) short short8;
typedef __attribute__((ext_vector_type(4))) float f32x4;

__device__ __forceinline__ float siluf_(float x){ return x/(1.f+expf(-x)); }
__device__ __forceinline__ float softplusf_(float x){ return fmaxf(x,0.f)+log1pf(expf(-fabsf(x))); }
__device__ __forceinline__ float geluf_(float x){ return 0.5f*x*(1.f+erff(x*0.70710678118654752f)); }

__device__ __forceinline__ void storev(float* p, float v){ *p = v; }
__device__ __forceinline__ void storev(__hip_bfloat16* p, float v){ *p = __float2bfloat16(v); }

// ---------------- weight conversion: f32 -> bf16 staging buffer ----------------
// wbuf layout (elements): [0,32768) in_proj_w; [32768,49152) out_proj_w;
// [49152,65536) fc1_w; [65536,81920) fc2_w; [81920,86016) xpw padded [2][16][128]
__global__ __launch_bounds__(256) void k_cvt(
    const float* __restrict__ ipw, const float* __restrict__ opw,
    const float* __restrict__ f1w, const float* __restrict__ f2w,
    const float* __restrict__ xpw, __hip_bfloat16* __restrict__ wbuf)
{
  int i = blockIdx.x*256 + threadIdx.x;
  if (i >= 86016) return;
  float v;
  if (i < 32768) v = ipw[i];
  else if (i < 49152) v = opw[i - 32768];
  else if (i < 65536) v = f1w[i - 49152];
  else if (i < 81920) v = f2w[i - 65536];
  else {
    int j = i - 81920;
    int d = j >> 11;          // /2048
    int rr = (j >> 7) & 15;   // row in [0,16)
    int k = j & 127;
    v = (rr < 10) ? xpw[(d*10 + rr)*128 + k] : 0.f;
  }
  wbuf[i] = __float2bfloat16(v);
}

// ---------------- prep: gather + LN + loan1 -> hpre bf16 [NTOK][128] ----------------
__global__ __launch_bounds__(128) void k_prep(
    const float* __restrict__ x, const float* __restrict__ xst,
    const int* __restrict__ curves,
    const float* __restrict__ loan1_w, const float* __restrict__ loan1_b,
    __hip_bfloat16* __restrict__ hpre)
{
  int token = blockIdx.x;
  int c = threadIdx.x;
  int b = token / (T_*P_);
  int t = (token / P_) % T_;
  int i = token % P_;
  int c0 = curves[(b*2 + 0)*P_ + i];
  size_t src = (size_t)(b*T_ + t)*P_ + c0;
  __shared__ float ssb[DSTAT];
  __shared__ float red[DIMM], red2[DIMM];
  float v = x[src*DIMM + c];
  if (c < DSTAT) ssb[c] = xst[src*DSTAT + c];
  red[c]=v; red2[c]=v*v;
  __syncthreads();
  for (int s=64; s>0; s>>=1){
    if (c < s){ red[c]+=red[c+s]; red2[c]+=red2[c+s]; }
    __syncthreads();
  }
  float m  = red[0]*(1.f/DIMM);
  float var = red2[0]*(1.f/DIMM) - m*m;
  float rs = rsqrtf(var + 1e-5f);
  float acc = loan1_b[c];
  #pragma unroll
  for (int j=0;j<DSTAT;j++) acc += ssb[j]*loan1_w[c*DSTAT+j];
  hpre[(size_t)token*DIMM + c] = __float2bfloat16((v - m)*rs + acc);
}

// ---------------- MFMA GEMM: C[M,N] = act(A[M,128] @ W[N,128]^T + bias) ----------------
// BM=96 (120000/96=1250 exact), BN=128, K=128 single stage, 4 waves.
template<typename OutT, int ACT, bool BIAS>
__global__ __launch_bounds__(256) void k_gemm_mfma(
    const __hip_bfloat16* __restrict__ A,
    const __hip_bfloat16* __restrict__ Wb,
    const float* __restrict__ bias,
    OutT* __restrict__ C, int N)
{
  __shared__ __hip_bfloat16 As[96][136];
  __shared__ __hip_bfloat16 Bs[128][136];
  const int tid = threadIdx.x;
  const size_t m0 = (size_t)blockIdx.x * 96;
  const int n0 = blockIdx.y * 128;
  #pragma unroll
  for (int p = 0; p < 6; ++p) {
    int ch = tid + p*256;
    int r = ch >> 4, c16 = ch & 15;
    uint4 v = *reinterpret_cast<const uint4*>(&A[(m0 + r)*128 + c16*8]);
    *reinterpret_cast<uint4*>(&As[r][c16*8]) = v;
  }
  #pragma unroll
  for (int p = 0; p < 8; ++p) {
    int ch = tid + p*256;
    int r = ch >> 4, c16 = ch & 15;
    uint4 v = *reinterpret_cast<const uint4*>(&Wb[(size_t)(n0 + r)*128 + c16*8]);
    *reinterpret_cast<uint4*>(&Bs[r][c16*8]) = v;
  }
  __syncthreads();
  const int wave = tid >> 6, lane = tid & 63;
  const int rb = (wave >> 1) * 48, cb = (wave & 1) * 64;
  const int lrow = lane & 15, koff = (lane >> 4) * 8;
  f32x4 acc[3][4];
  #pragma unroll
  for (int i=0;i<3;i++)
    #pragma unroll
    for (int j=0;j<4;j++) acc[i][j] = f32x4{0.f,0.f,0.f,0.f};
  #pragma unroll
  for (int kb = 0; kb < 4; ++kb) {
    short8 a[3], bfr[4];
    #pragma unroll
    for (int i=0;i<3;i++) a[i] = *reinterpret_cast<const short8*>(&As[rb + i*16 + lrow][kb*32 + koff]);
    #pragma unroll
    for (int j=0;j<4;j++) bfr[j] = *reinterpret_cast<const short8*>(&Bs[cb + j*16 + lrow][kb*32 + koff]);
    #pragma unroll
    for (int i=0;i<3;i++)
      #pragma unroll
      for (int j=0;j<4;j++)
        acc[i][j] = __builtin_amdgcn_mfma_f32_16x16x32_bf16(a[i], bfr[j], acc[i][j], 0,0,0);
  }
  const int crow0 = (lane >> 4) * 4, ccol = lane & 15;
  #pragma unroll
  for (int i=0;i<3;i++){
    #pragma unroll
    for (int j=0;j<4;j++){
      int n = n0 + cb + j*16 + ccol;
      float bv = BIAS ? bias[n] : 0.f;
      #pragma unroll
      for (int r=0;r<4;r++){
        size_t m = m0 + rb + i*16 + crow0 + r;
        float v = acc[i][j][r] + bv;
        if (ACT==1) v = geluf_(v);
        storev(&C[m*N + n], v);
      }
    }
  }
}

// ---------------- fused conv + xproj(MFMA) + scan, per window per dir ----------------
__global__ __launch_bounds__(128) void k_scan(
    const __hip_bfloat16* __restrict__ H,      // [NTOK][256] bf16
    const float* __restrict__ conv_w, const float* __restrict__ conv_b,
    const __hip_bfloat16* __restrict__ xpw_bf, // [2][16][128] bf16 (rows>=10 zero)
    const float* __restrict__ dt_w, const float* __restrict__ dt_b,
    const float* __restrict__ A_log, const float* __restrict__ Dp,
    __hip_bfloat16* __restrict__ Y)            // [2][NWIN][30][128] bf16
{
  const int bid = blockIdx.x;
  const int dir = bid / NWIN;
  const int n   = bid % NWIN;
  const int c = threadIdx.x;
  const int b  = n / 2000;
  const int a  = (n / 1000) & 1;
  const int qw = n % 1000;
  __shared__ __hip_bfloat16 u_bf[32][136];
  __shared__ float dbl_s[32][20];

  const int row0 = (b*T_ + a*G0_)*P_;  // + (l/10)*P_ + p
  // load xh, conv, silu
  float xh[LWIN];
  #pragma unroll
  for (int l=0;l<LWIN;l++){
    int pf = qw*G1_ + l%G1_;
    int p  = dir ? (P_-1-pf) : pf;
    size_t base = ((size_t)(row0 + (l/G1_)*P_ + p))*256;
    xh[l] = __bfloat162float(H[base + c]);
  }
  float w0 = conv_w[(dir*DIMM + c)*DCONV + 0];
  float w1 = conv_w[(dir*DIMM + c)*DCONV + 1];
  float w2 = conv_w[(dir*DIMM + c)*DCONV + 2];
  float cbv = conv_b[dir*DIMM + c];
  float u[LWIN];
  #pragma unroll
  for (int l=0;l<LWIN;l++){
    float xm2 = (l>=2)? xh[l-2] : 0.f;
    float xm1 = (l>=1)? xh[l-1] : 0.f;
    u[l] = siluf_(w0*xm2 + w1*xm1 + w2*xh[l] + cbv);
  }
  #pragma unroll
  for (int l=0;l<LWIN;l++) u_bf[l][c] = __float2bfloat16(u[l]);
  u_bf[30][c] = __float2bfloat16(0.f);
  u_bf[31][c] = __float2bfloat16(0.f);
  __syncthreads();

  // xproj via MFMA: dbl[32 rows l][16 cols j] = u[32x128] @ xpw[16x128]^T
  {
    const int wave = c >> 6, lane = c & 63;
    const int lrow = lane & 15, koff = (lane >> 4) * 8;
    const int arow = wave*16 + lrow;
    f32x4 acc = {0.f,0.f,0.f,0.f};
    #pragma unroll
    for (int kb=0; kb<4; ++kb){
      short8 av = *reinterpret_cast<const short8*>(&u_bf[arow][kb*32 + koff]);
      short8 bv = *reinterpret_cast<const short8*>(&xpw_bf[(size_t)(dir*16 + lrow)*128 + kb*32 + koff]);
      acc = __builtin_amdgcn_mfma_f32_16x16x32_bf16(av, bv, acc, 0,0,0);
    }
    const int r0 = wave*16 + (lane>>4)*4, col = lane & 15;
    #pragma unroll
    for (int r=0;r<4;r++) dbl_s[r0+r][col] = acc[r];
  }
  __syncthreads();

  // scan per channel
  float dtw[8];
  #pragma unroll
  for (int r2=0;r2<8;r2++) dtw[r2] = dt_w[dir*DIMM*8 + c*8 + r2];
  float dtbv = dt_b[dir*DIMM + c];
  float Av = -expf(A_log[dir*DIMM + c]);
  float Dv = Dp[dir*DIMM + c];
  // z preload
  float z[LWIN];
  #pragma unroll
  for (int l=0;l<LWIN;l++){
    int pf = qw*G1_ + l%G1_;
    int p  = dir ? (P_-1-pf) : pf;
    size_t base = ((size_t)(row0 + (l/G1_)*P_ + p))*256;
    z[l] = __bfloat162float(H[base + 128 + c]);
  }
  float hst = 0.f;
  __hip_bfloat16* Yp = Y + ((size_t)dir*NWIN + n)*LWIN*DIMM;
  #pragma unroll
  for (int l=0;l<LWIN;l++){
    float dtv = dtbv;
    #pragma unroll
    for (int r2=0;r2<8;r2++) dtv += dbl_s[l][r2]*dtw[r2];
    float delta = softplusf_(dtv);
    float uv = u[l];
    hst = expf(delta*Av)*hst + (delta*uv)*dbl_s[l][8];
    float y = hst*dbl_s[l][9] + uv*Dv;
    y *= siluf_(z[l]);
    Yp[l*DIMM + c] = __float2bfloat16(y);
  }
}

// ---------------- combine with the scrambled _wrev mapping ----------------
__device__ __forceinline__ int win_index(int t, int p){
  int G  = t*P_ + p;
  int d3 = G / 6000;
  int r  = G % 6000;
  int d1 = r / 6;
  int r2 = r % 6;
  int d4 = r2 >> 1;
  int d2 = r2 & 1;
  int F  = d1*60 + d2*30 + d3*3 + d4;
  int a  = F / 30000;
  int F2 = F % 30000;
  int qw = F2 / 30;
  int l  = F2 % 30;
  return (a*1000 + qw)*LWIN + l;
}

__global__ __launch_bounds__(256) void k_combine(
    const __hip_bfloat16* __restrict__ Y, __hip_bfloat16* __restrict__ yc)
{
  int tid = threadIdx.x;
  int token = blockIdx.x*4 + (tid>>6);
  int lane = tid & 63;
  int b = token/(T_*P_); int rem = token%(T_*P_);
  int t = rem/P_, p = rem%P_;
  size_t bbase = (size_t)b*2000*LWIN;
  int wf = win_index(t, p);
  int wb = win_index(t, P_-1-p);
  const __hip_bfloat16* Yf = Y;
  const __hip_bfloat16* Yb = Y + (size_t)NWIN*LWIN*DIMM;
  __hip_bfloat162 fv = *reinterpret_cast<const __hip_bfloat162*>(&Yf[(bbase + wf)*DIMM + lane*2]);
  __hip_bfloat162 bv = *reinterpret_cast<const __hip_bfloat162*>(&Yb[(bbase + wb)*DIMM + lane*2]);
  __hip_bfloat162 o;
  o.x = __float2bfloat16(0.5f*(__bfloat162float(fv.x)+__bfloat162float(bv.x)));
  o.y = __float2bfloat16(0.5f*(__bfloat162float(fv.y)+__bfloat162float(bv.y)));
  *reinterpret_cast<__hip_bfloat162*>(&yc[(size_t)token*DIMM + lane*2]) = o;
}

// ---------------- mid: x1 = xs + yproj ; g = LN(x1) + loan2 ----------------
__global__ __launch_bounds__(128) void k_mid(
    const float* __restrict__ x, const float* __restrict__ xst,
    const int* __restrict__ curves,
    const float* __restrict__ yproj,
    const float* __restrict__ loan2_w, const float* __restrict__ loan2_b,
    float* __restrict__ x1, __hip_bfloat16* __restrict__ g)
{
  int token = blockIdx.x;
  int c = threadIdx.x;
  int b = token / (T_*P_);
  int t = (token / P_) % T_;
  int i = token % P_;
  int c0 = curves[(b*2 + 0)*P_ + i];
  size_t src = (size_t)(b*T_ + t)*P_ + c0;
  __shared__ float ssb[DSTAT];
  __shared__ float red[DIMM], red2[DIMM];
  float v = x[src*DIMM + c] + yproj[(size_t)token*DIMM + c];
  x1[(size_t)token*DIMM + c] = v;
  if (c < DSTAT) ssb[c] = xst[src*DSTAT + c];
  red[c]=v; red2[c]=v*v;
  __syncthreads();
  for (int s=64; s>0; s>>=1){
    if (c < s){ red[c]+=red[c+s]; red2[c]+=red2[c+s]; }
    __syncthreads();
  }
  float m  = red[0]*(1.f/DIMM);
  float var = red2[0]*(1.f/DIMM) - m*m;
  float rs = rsqrtf(var + 1e-5f);
  float acc = loan2_b[c];
  #pragma unroll
  for (int j=0;j<DSTAT;j++) acc += ssb[j]*loan2_w[c*DSTAT+j];
  g[(size_t)token*DIMM + c] = __float2bfloat16((v - m)*rs + acc);
}

// ---------------- final: x2 = x1 + h2, gather by c1 ----------------
__global__ __launch_bounds__(128) void k_final(
    const float* __restrict__ x1, const float* __restrict__ h2,
    const int* __restrict__ curves, float* __restrict__ out)
{
  int token = blockIdx.x; int c = threadIdx.x;
  int b = token/(T_*P_); int rem = token%(T_*P_);
  int t = rem/P_, i = rem%P_;
  int c1 = curves[(b*2+1)*P_ + i];
  size_t src = (size_t)(b*T_+t)*P_ + c1;
  out[(size_t)token*DIMM + c] = x1[src*DIMM + c] + h2[src*DIMM + c];
}

extern "C" void kernel_launch(void* const* d_in, const int* in_sizes, int n_in,
                              void* d_out, int out_size, void* d_ws, size_t ws_size,
                              hipStream_t stream) {
  const float* x        = (const float*)d_in[0];
  const float* xst      = (const float*)d_in[1];
  const int*   curves   = (const int*)  d_in[2];
  const float* loan1_w  = (const float*)d_in[3];
  const float* loan1_b  = (const float*)d_in[4];
  const float* loan2_w  = (const float*)d_in[5];
  const float* loan2_b  = (const float*)d_in[6];
  const float* in_proj_w  = (const float*)d_in[7];
  const float* out_proj_w = (const float*)d_in[8];
  const float* conv_w   = (const float*)d_in[9];
  const float* conv_b   = (const float*)d_in[10];
  const float* xproj_w  = (const float*)d_in[11];
  const float* dt_w     = (const float*)d_in[12];
  const float* dt_b     = (const float*)d_in[13];
  const float* A_log    = (const float*)d_in[14];
  const float* Dvec     = (const float*)d_in[15];
  const float* fc1_w    = (const float*)d_in[16];
  const float* fc1_b    = (const float*)d_in[17];
  const float* fc2_w    = (const float*)d_in[18];
  const float* fc2_b    = (const float*)d_in[19];
  float* out = (float*)d_out;

  char* ws = (char*)d_ws;
  // region A [0, 61.44MB): hpre(bf16) -> Y(bf16) -> yproj(f32) -> h2(f32)
  // region B [61.44, 122.88MB): H(bf16) -> x1(f32)
  // region C [122.88, 153.6MB): ycomb(bf16) -> gmid(bf16)
  // region D [153.6, 184.32MB): a1(bf16)
  // region E [184.32MB, +172KB): bf16 weights
  const size_t RB = 61440000, RC = 122880000, RD = 153600000, RE = 184320000;
  __hip_bfloat16* hpre = (__hip_bfloat16*)(ws + 0);
  __hip_bfloat16* Ybuf = (__hip_bfloat16*)(ws + 0);
  float*          yproj= (float*)(ws + 0);
  float*          h2   = (float*)(ws + 0);
  __hip_bfloat16* Hbf  = (__hip_bfloat16*)(ws + RB);
  float*          x1   = (float*)(ws + RB);
  __hip_bfloat16* ycomb= (__hip_bfloat16*)(ws + RC);
  __hip_bfloat16* gmid = (__hip_bfloat16*)(ws + RC);
  __hip_bfloat16* a1   = (__hip_bfloat16*)(ws + RD);
  __hip_bfloat16* wbuf = (__hip_bfloat16*)(ws + RE);
  __hip_bfloat16* ipw_bf = wbuf;
  __hip_bfloat16* opw_bf = wbuf + 32768;
  __hip_bfloat16* f1w_bf = wbuf + 49152;
  __hip_bfloat16* f2w_bf = wbuf + 65536;
  __hip_bfloat16* xpw_bf = wbuf + 81920;

  k_cvt<<<336, 256, 0, stream>>>(in_proj_w, out_proj_w, fc1_w, fc2_w, xproj_w, wbuf);
  k_prep<<<NTOK, 128, 0, stream>>>(x, xst, curves, loan1_w, loan1_b, hpre);

  dim3 g1(NTOK/96, 2);
  k_gemm_mfma<__hip_bfloat16,0,false><<<g1, 256, 0, stream>>>(hpre, ipw_bf, nullptr, Hbf, 256);

  k_scan<<<2*NWIN, 128, 0, stream>>>(Hbf, conv_w, conv_b, xpw_bf, dt_w, dt_b, A_log, Dvec, Ybuf);

  k_combine<<<NTOK/4, 256, 0, stream>>>(Ybuf, ycomb);

  dim3 g2(NTOK/96, 1);
  k_gemm_mfma<float,0,false><<<g2, 256, 0, stream>>>(ycomb, opw_bf, nullptr, yproj, 128);

  k_mid<<<NTOK, 128, 0, stream>>>(x, xst, curves, yproj, loan2_w, loan2_b, x1, gmid);

  k_gemm_mfma<__hip_bfloat16,1,true><<<g2, 256, 0, stream>>>(gmid, f1w_bf, fc1_b, a1, 128);
  k_gemm_mfma<float,0,true><<<g2, 256, 0, stream>>>(a1, f2w_bf, fc2_b, h2, 128);

  k_final<<<NTOK, 128, 0, stream>>>(x1, h2, curves, out);
}